// Round 11
// baseline (351.240 us; speedup 1.0000x reference)
//
#include <hip/hip_runtime.h>
#include <stdint.h>

// Disable FMA contraction file-wide: we must replicate the reference's
// per-op f32 rounding (decode + IoU) to avoid NMS decision flips.
#pragma clang fp contract(off)

#define B_IMGS   4
#define NLVL     5
#define A_TOTAL  242991
#define NSEL     4741          // 1000*4 + 741
#define NBUCK    8192          // 13-bit buckets: sign+exp+4 mantissa (os>>19)
#define BSHIFT   19
#define CAND_CAP 2048
#define POST_NMS 1000
#define NBL      (B_IMGS * NLVL)
#define NMS_TH   0.7f
#define NEGV     (-1e10f)
#define W_IMGF   1216.0f
#define H_IMGF   800.0f
#define MIN_SZ   1e-3f
#define BBOX_CLIP 4.135166556742356f   // log(1000/16), rounded to f32 by compiler

// ---------- level helpers ----------
__device__ __forceinline__ int lvl_k(int l) { return (l == 4) ? 741 : 1000; }

// ---------- order-preserving float<->uint ----------
__device__ __forceinline__ unsigned flipf(float f) {
    unsigned u = __float_as_uint(f);
    return u ^ (unsigned)(((int)u >> 31) | 0x80000000);
}
__device__ __forceinline__ float unflipf(unsigned os) {
    unsigned u = (os & 0x80000000u) ? (os ^ 0x80000000u) : ~os;
    return __uint_as_float(u);
}

// ---------- workspace layout ----------
static constexpr size_t SZ_HIST    = (size_t)NBL * NBUCK * sizeof(unsigned);        // 655,360
static constexpr size_t OFF_CNT    = SZ_HIST;                                        // +80
static constexpr size_t OFF_BOXMAX = OFF_CNT + NBL * sizeof(unsigned);               // +16
static constexpr size_t ZERO_BYTES = OFF_BOXMAX + B_IMGS * sizeof(unsigned);
static constexpr size_t OFF_CAND   = (ZERO_BYTES + 15) & ~(size_t)15;
static constexpr size_t OFF_SEL    = OFF_CAND + (size_t)NBL * CAND_CAP * 8;
static constexpr size_t OFF_BOXR   = OFF_SEL + (size_t)B_IMGS * NSEL * 8;
static constexpr size_t OFF_SCR    = OFF_BOXR + (size_t)B_IMGS * NSEL * 16;
static constexpr size_t OFF_BOXL   = OFF_SCR + (size_t)B_IMGS * NSEL * 4;
static constexpr size_t OFF_VAL    = OFF_BOXL + (size_t)B_IMGS * NSEL * 16;
static constexpr size_t OFF_RMAP   = OFF_VAL + (size_t)B_IMGS * NSEL * 4;
static constexpr size_t OFF_KEEP   = OFF_RMAP + (size_t)B_IMGS * NSEL * 4;
static constexpr size_t WS_NEED    = OFF_KEEP + (size_t)B_IMGS * NSEL * 4;           // ~1.1 MB

// ---------- K1: per-(b,level) LDS histogram, merged to global ----------
// 34 blocks per image, 512 threads, each covering one (level, sub-chunk) span.
#define HBLK_PER_IMG 34
__global__ void k_hist(const float* __restrict__ obj, unsigned* __restrict__ hist) {
    __shared__ unsigned lh[NBUCK];   // 32 KB
    const int tid = threadIdx.x;     // 512
    const int b = blockIdx.x / HBLK_PER_IMG;
    const int r = blockIdx.x - b * HBLK_PER_IMG;
    int l, sub, chunk, lstart, n;
    if (r < 24)      { l = 0; sub = r;      chunk = 7600; lstart = 0;      n = 182400; }
    else if (r < 30) { l = 1; sub = r - 24; chunk = 7600; lstart = 182400; n = 45600; }
    else if (r < 32) { l = 2; sub = r - 30; chunk = 5700; lstart = 228000; n = 11400; }
    else if (r == 32){ l = 3; sub = 0;      chunk = 2850; lstart = 239400; n = 2850; }
    else             { l = 4; sub = 0;      chunk = 741;  lstart = 242250; n = 741; }
    #pragma unroll
    for (int i = tid; i < NBUCK; i += 512) lh[i] = 0;
    __syncthreads();
    const int s0 = sub * chunk;
    const int cnt = min(chunk, n - s0);
    const float* src = obj + (size_t)b * A_TOTAL + lstart + s0;
    for (int i = tid; i < cnt; i += 512) {
        unsigned os = flipf(src[i]);
        atomicAdd(&lh[os >> BSHIFT], 1u);
    }
    __syncthreads();
    unsigned* gh = hist + (size_t)(b * NLVL + l) * NBUCK;
    for (int i = tid; i < NBUCK; i += 512) {
        unsigned v = lh[i];
        if (v) atomicAdd(&gh[i], v);
    }
}

// ---------- K2: compact candidates (threshold scan fused in-prologue) ----------
// One (b,level,sub-span) per block. Each block redundantly computes its bl's
// threshold from the global histogram (written by the PREVIOUS kernel ->
// kernel-boundary visibility). Passes staged in LDS, one global atomicAdd
// per block, coalesced copy-out. Order within cand[bl] is arbitrary.
#define CBLK_PER_IMG 65
__global__ void k_compact(const float* __restrict__ obj, const unsigned* __restrict__ hist,
                          unsigned* __restrict__ cnt, unsigned long long* __restrict__ cand) {
    __shared__ unsigned long long sbuf[CAND_CAP];   // 16 KB staging
    __shared__ unsigned part[256];
    __shared__ unsigned chunkbuf[32];
    __shared__ int s_chunk;
    __shared__ unsigned s_cum, s_thr, lcnt, gbase;
    const int tid = threadIdx.x;     // 256
    const int b = blockIdx.x / CBLK_PER_IMG;
    const int r = blockIdx.x - b * CBLK_PER_IMG;
    int l, sub, chunk, lstart, n;
    if (r < 48)      { l = 0; sub = r;      chunk = 3800; lstart = 0;      n = 182400; }
    else if (r < 60) { l = 1; sub = r - 48; chunk = 3800; lstart = 182400; n = 45600; }
    else if (r < 63) { l = 2; sub = r - 60; chunk = 3800; lstart = 228000; n = 11400; }
    else if (r == 63){ l = 3; sub = 0;      chunk = 2850; lstart = 239400; n = 2850; }
    else             { l = 4; sub = 0;      chunk = 741;  lstart = 242250; n = 741; }
    const int bl = b * NLVL + l;
    const int kl = lvl_k(l);
    // ---- fused threshold scan (identical in all blocks of this bl) ----
    const unsigned* h = hist + (size_t)bl * NBUCK;
    {
        unsigned s = 0;
        for (int i = 0; i < 32; ++i) s += h[tid * 32 + i];
        part[tid] = s;
    }
    if (tid == 0) lcnt = 0;
    __syncthreads();
    if (tid == 0) {
        unsigned cum = 0;
        int t = 255;
        for (; t > 0; --t) {
            if (cum + part[t] >= (unsigned)kl) break;
            cum += part[t];
        }
        s_chunk = t;
        s_cum = cum;
    }
    __syncthreads();
    if (tid < 32) chunkbuf[tid] = h[s_chunk * 32 + tid];
    __syncthreads();
    if (tid == 0) {
        unsigned c2 = s_cum;
        int T = s_chunk * 32;
        for (int i = 31; i >= 0; --i) {
            c2 += chunkbuf[i];
            if (c2 >= (unsigned)kl) { T = s_chunk * 32 + i; break; }
        }
        s_thr = (unsigned)T;
    }
    __syncthreads();
    const unsigned T = s_thr;
    // ---- pass filter into LDS staging ----
    const int s0 = sub * chunk;
    const int m = min(chunk, n - s0);
    const int abase = lstart + s0;
    const float* src = obj + (size_t)b * A_TOTAL + abase;
    for (int i = tid; i < m; i += 256) {
        unsigned os = flipf(src[i]);
        if ((os >> BSHIFT) >= T) {
            unsigned slot = atomicAdd(&lcnt, 1u);
            if (slot < CAND_CAP)
                sbuf[slot] = (((unsigned long long)(~os)) << 32) | (unsigned)(abase + i);
        }
    }
    __syncthreads();
    unsigned total = lcnt; if (total > CAND_CAP) total = CAND_CAP;
    if (tid == 0) gbase = atomicAdd(&cnt[bl], total);
    __syncthreads();
    const unsigned gb = gbase;
    for (unsigned i = tid; i < total; i += 256) {
        unsigned g = gb + i;
        if (g < CAND_CAP)
            cand[(size_t)bl * CAND_CAP + g] = sbuf[i];
    }
}

// ---------- K3: per-(b,level) bitonic sort of candidates; keep top-k ----------
// v3: 1024 threads — exactly one compare-swap per thread per step.
__global__ void k_sortlevel(const unsigned long long* __restrict__ cand,
                            const unsigned* __restrict__ cnt,
                            unsigned long long* __restrict__ sel) {
    __shared__ unsigned long long keys[CAND_CAP];
    const int bl = blockIdx.x;
    const int b = bl / NLVL, l = bl - (bl / NLVL) * NLVL;
    const int tid = threadIdx.x;     // 1024
    int m = (int)cnt[bl];
    if (m > CAND_CAP) m = CAND_CAP;
    for (int i = tid; i < CAND_CAP; i += 1024)
        keys[i] = (i < m) ? cand[(size_t)bl * CAND_CAP + i] : ~0ULL;
    __syncthreads();
    for (int k = 2; k <= CAND_CAP; k <<= 1) {
        for (int j = k >> 1; j > 0; j >>= 1) {
            int i = ((tid / j) * (j << 1)) + (tid % j);
            int p = i + j;
            bool up = ((i & k) == 0);
            unsigned long long a = keys[i], c = keys[p];
            if ((a > c) == up) { keys[i] = c; keys[p] = a; }
            __syncthreads();
        }
    }
    int kl = lvl_k(l);
    for (int q = tid; q < kl; q += 1024)
        sel[(size_t)b * NSEL + l * 1000 + q] = keys[q];
}

// ---------- binary search in LDS: #elements < key ----------
__device__ __forceinline__ int lbound_lds(const unsigned long long* s, int len,
                                          unsigned long long key) {
    int lo = 0, hi = len;
    while (lo < hi) {
        int mid = (lo + hi) >> 1;
        if (s[mid] < key) lo = mid + 1; else hi = mid;
    }
    return lo;
}

// ---------- K4: decode+clip+valid; global rank via LDS 5-way merge-rank ----------
// grid (5, b) x 1024 threads — skey staged once per 1024 entries.
__global__ void k_decode(const float* __restrict__ deltas, const float* __restrict__ anchors,
                         const unsigned long long* __restrict__ sel,
                         float* __restrict__ boxes_r, float* __restrict__ score_r,
                         float* __restrict__ boxes_l, int* __restrict__ valid_l,
                         int* __restrict__ rankmap, unsigned* __restrict__ boxmax) {
    __shared__ unsigned long long skey[NSEL];     // 37,928 B
    __shared__ float wmax[16];
    const int b = blockIdx.y;
    const int tid = threadIdx.x;                  // 1024
    for (int i = tid; i < NSEL; i += 1024)
        skey[i] = sel[(size_t)b * NSEL + i];
    __syncthreads();

    int p = blockIdx.x * 1024 + tid;
    bool on = p < NSEL;
    float mx = 0.0f;
    if (on) {
        int l = p / 1000;           // p in [4000,4741) -> 4
        int q = p - l * 1000;
        unsigned long long key = skey[p];
        unsigned a = (unsigned)(key & 0xFFFFFFFFu);
        unsigned os = ~((unsigned)(key >> 32));
        if (a >= A_TOTAL) a = 0;    // impossible-path safety (MAX padding)
        float score = unflipf(os);
        // global rank = q + sum over other levels of (#keys < key)
        int r = q;
        for (int l2 = 0; l2 < NLVL; ++l2) {
            if (l2 == l) continue;
            r += lbound_lds(skey + l2 * 1000, lvl_k(l2), key);
        }
        // decode (replicates reference op order; contraction disabled)
        const float* dv = deltas + ((size_t)b * A_TOTAL + a) * 4;
        const float* av = anchors + (size_t)a * 4;
        float ax1 = av[0], ay1 = av[1], ax2 = av[2], ay2 = av[3];
        float wa = ax2 - ax1, ha = ay2 - ay1;
        float cxa = ax1 + 0.5f * wa, cya = ay1 + 0.5f * ha;
        float dx = dv[0], dy = dv[1];
        float dw = fminf(dv[2], BBOX_CLIP), dh = fminf(dv[3], BBOX_CLIP);
        float cx = dx * wa + cxa, cy = dy * ha + cya;
        float w = expf(dw) * wa, h = expf(dh) * ha;
        float x1 = cx - 0.5f * w, y1 = cy - 0.5f * h;
        float x2 = cx + 0.5f * w, y2 = cy + 0.5f * h;
        float x1c = fminf(fmaxf(x1, 0.0f), W_IMGF);
        float y1c = fminf(fmaxf(y1, 0.0f), H_IMGF);
        float x2c = fminf(fmaxf(x2, 0.0f), W_IMGF);
        float y2c = fminf(fmaxf(y2, 0.0f), H_IMGF);
        int valid = ((x2c - x1c) >= MIN_SZ) && ((y2c - y1c) >= MIN_SZ);
        mx = fmaxf(fmaxf(x1c, y1c), fmaxf(x2c, y2c));
        size_t rp = (size_t)b * NSEL + r;
        boxes_r[rp * 4 + 0] = x1c; boxes_r[rp * 4 + 1] = y1c;
        boxes_r[rp * 4 + 2] = x2c; boxes_r[rp * 4 + 3] = y2c;
        score_r[rp] = score;
        size_t pp = (size_t)b * NSEL + p;
        boxes_l[pp * 4 + 0] = x1c; boxes_l[pp * 4 + 1] = y1c;
        boxes_l[pp * 4 + 2] = x2c; boxes_l[pp * 4 + 3] = y2c;
        valid_l[pp] = valid;
        rankmap[pp] = r;
    }
    // block max reduction -> single device atomic (coords >= 0: bit order == value order)
    #pragma unroll
    for (int o = 32; o > 0; o >>= 1)
        mx = fmaxf(mx, __shfl_xor(mx, o));
    if ((tid & 63) == 0) wmax[tid >> 6] = mx;
    __syncthreads();
    if (tid == 0) {
        float m2 = wmax[0];
        #pragma unroll
        for (int i = 1; i < 16; ++i) m2 = fmaxf(m2, wmax[i]);
        atomicMax(boxmax + b, __float_as_uint(m2));
    }
}

// ---------- K5: fused NMS (mask + greedy resolve, no materialized mask) ----------
// One block (1024 threads) per (b,level). Boxes in LDS SoA (broadcast-free IoU).
// Per 64-chunk: (a) all threads build the 64x64 diag block via LDS atomicOr,
// (b) wave 0 runs the serial readlane chain (nz-filtered), (c) all threads
// apply chunk-c kept rows to future columns on the fly (thread = column).
__global__ void k_nms(const float* __restrict__ boxes_l, const int* __restrict__ valid_l,
                      const int* __restrict__ rankmap, const unsigned* __restrict__ boxmax,
                      int* __restrict__ keep_r) {
    __shared__ float sx1[1000], sy1[1000], sx2[1000], sy2[1000], sar[1000];  // 20 KB
    __shared__ unsigned long long keepw[16];
    __shared__ unsigned long long diag[64];
    const int bl = blockIdx.x;
    const int b = bl / NLVL, l = bl - b * NLVL;
    const int kl = lvl_k(l);
    const int t = threadIdx.x;       // 1024
    const int base = b * NSEL + l * 1000;
    const float M = __uint_as_float(boxmax[b]) + 1.0f;
    const float off = (float)l * M;

    if (t < 16) keepw[t] = 0ULL;
    __syncthreads();
    if (t < kl) {
        const float4 bx = *(const float4*)(boxes_l + (size_t)(base + t) * 4);
        float x1 = bx.x + off, y1 = bx.y + off, x2 = bx.z + off, y2 = bx.w + off;
        sx1[t] = x1; sy1[t] = y1; sx2[t] = x2; sy2[t] = y2;
        sar[t] = (x2 - x1) * (y2 - y1);
        if (valid_l[base + t])
            atomicOr(&keepw[t >> 6], 1ULL << (t & 63));
    }
    __syncthreads();

    const int nch = (kl + 63) >> 6;   // 16 or 12
    for (int c = 0; c < nch; ++c) {
        // (a) diagonal 64x64 block: thread -> (row r, 4-col group sg)
        if (t < 64) diag[t] = 0ULL;
        __syncthreads();
        {
            int r = t >> 4, sg = t & 15;
            int i = c * 64 + r;
            if (i < kl) {
                float ix1 = sx1[i], iy1 = sy1[i], ix2 = sx2[i], iy2 = sy2[i], ai = sar[i];
                unsigned long long nib = 0;
                #pragma unroll
                for (int k = 0; k < 4; ++k) {
                    int s = sg * 4 + k;
                    int j = c * 64 + s;
                    if (j > i && j < kl) {
                        float ltx = fmaxf(ix1, sx1[j]), lty = fmaxf(iy1, sy1[j]);
                        float rbx = fminf(ix2, sx2[j]), rby = fminf(iy2, sy2[j]);
                        float ww = fmaxf(rbx - ltx, 0.0f), hh = fmaxf(rby - lty, 0.0f);
                        float inter = ww * hh;
                        float iou = inter / ((ai + sar[j]) - inter);  // NaN>th==false, matches jnp
                        if (iou > NMS_TH) nib |= (1ULL << s);
                    }
                }
                if (nib) atomicOr(&diag[r], nib);
            }
        }
        __syncthreads();
        // (b) serial within-chunk greedy on wave 0 (readlane chain, nz filter)
        if (t < 64) {
            unsigned long long dw = diag[t];
            unsigned dlo = (unsigned)dw, dhi = (unsigned)(dw >> 32);
            unsigned long long kw = keepw[c];
            unsigned long long nz = __ballot(dw != 0ULL);
            unsigned long long rem = kw & nz;
            while (rem) {
                int r = __ffsll((long long)rem) - 1;
                unsigned lo = __builtin_amdgcn_readlane(dlo, r);
                unsigned hi = __builtin_amdgcn_readlane(dhi, r);
                unsigned long long d = ((unsigned long long)hi << 32) | lo;
                kw &= ~d;
                rem &= ~(d | (1ULL << r));
            }
            if (t == 0) keepw[c] = kw;
        }
        __syncthreads();
        // (c) chunk-c kept rows suppress future columns (thread = column j)
        if (c + 1 < nch) {
            unsigned long long kwc = keepw[c];        // uniform broadcast read
            const int j = t;
            const bool on = (j >= (c + 1) * 64) && (j < kl);
            float jx1 = 0, jy1 = 0, jx2 = 0, jy2 = 0, aj = 0;
            if (on) { jx1 = sx1[j]; jy1 = sy1[j]; jx2 = sx2[j]; jy2 = sy2[j]; aj = sar[j]; }
            while (kwc) {
                int r = __ffsll((long long)kwc) - 1;
                kwc &= kwc - 1;
                int i = c * 64 + r;
                float ix1 = sx1[i], iy1 = sy1[i], ix2 = sx2[i], iy2 = sy2[i], ai = sar[i];
                if (on) {
                    float ltx = fmaxf(ix1, jx1), lty = fmaxf(iy1, jy1);
                    float rbx = fminf(ix2, jx2), rby = fminf(iy2, jy2);
                    float ww = fmaxf(rbx - ltx, 0.0f), hh = fmaxf(rby - lty, 0.0f);
                    float inter = ww * hh;
                    float iou = inter / ((ai + aj) - inter);
                    if (iou > NMS_TH)
                        atomicAnd(&keepw[j >> 6], ~(1ULL << (j & 63)));
                }
            }
        }
        __syncthreads();
    }
    // scatter keep bits to global-rank order
    if (t < kl) {
        int bit = (int)((keepw[t >> 6] >> (t & 63)) & 1ULL);
        keep_r[b * NSEL + rankmap[base + t]] = bit;
    }
}

// ---------- K6: compact kept entries (score order) into output ----------
__global__ void k_output(const int* __restrict__ keep_r, const float* __restrict__ boxes_r,
                         const float* __restrict__ score_r, float* __restrict__ out) {
    int b = blockIdx.x, tid = threadIdx.x;
    float* ob = out + (size_t)b * POST_NMS * 4;
    float* osc = out + (size_t)B_IMGS * POST_NMS * 4 + (size_t)b * POST_NMS;
    for (int p = tid; p < POST_NMS; p += 256) {
        ob[p * 4 + 0] = 0.0f; ob[p * 4 + 1] = 0.0f;
        ob[p * 4 + 2] = 0.0f; ob[p * 4 + 3] = 0.0f;
        osc[p] = NEGV;
    }
    __syncthreads();   // global writes drained before barrier (vmcnt)
    const int CH = 19; // 19*256 = 4864 >= 4741
    int base = tid * CH;
    int cnt = 0;
    for (int k = 0; k < CH; ++k) {
        int r = base + k;
        if (r < NSEL) cnt += keep_r[b * NSEL + r];
    }
    __shared__ int ps[256];
    ps[tid] = cnt;
    __syncthreads();
    for (int ofs = 1; ofs < 256; ofs <<= 1) {
        int v = (tid >= ofs) ? ps[tid - ofs] : 0;
        __syncthreads();
        ps[tid] += v;
        __syncthreads();
    }
    int p = ps[tid] - cnt;   // exclusive prefix
    for (int k = 0; k < CH; ++k) {
        int r = base + k;
        if (r < NSEL && keep_r[b * NSEL + r]) {
            if (p < POST_NMS) {
                const float* bp = boxes_r + ((size_t)b * NSEL + r) * 4;
                ob[p * 4 + 0] = bp[0]; ob[p * 4 + 1] = bp[1];
                ob[p * 4 + 2] = bp[2]; ob[p * 4 + 3] = bp[3];
                osc[p] = score_r[(size_t)b * NSEL + r];
            }
            ++p;
        }
    }
}

extern "C" void kernel_launch(void* const* d_in, const int* in_sizes, int n_in,
                              void* d_out, int out_size, void* d_ws, size_t ws_size,
                              hipStream_t stream) {
    const float* obj     = (const float*)d_in[0];   // [4, 242991]
    const float* deltas  = (const float*)d_in[1];   // [4, 242991, 4]
    const float* anchors = (const float*)d_in[2];   // [242991, 4]
    float* out = (float*)d_out;                     // [4,1000,4] ++ [4,1000]

    char* ws = (char*)d_ws;
    unsigned*            hist    = (unsigned*)(ws);
    unsigned*            cnt     = (unsigned*)(ws + OFF_CNT);
    unsigned*            boxmax  = (unsigned*)(ws + OFF_BOXMAX);
    unsigned long long*  cand    = (unsigned long long*)(ws + OFF_CAND);
    unsigned long long*  sel     = (unsigned long long*)(ws + OFF_SEL);
    float*               boxes_r = (float*)(ws + OFF_BOXR);
    float*               score_r = (float*)(ws + OFF_SCR);
    float*               boxes_l = (float*)(ws + OFF_BOXL);
    int*                 valid_l = (int*)(ws + OFF_VAL);
    int*                 rankmap = (int*)(ws + OFF_RMAP);
    int*                 keep_r  = (int*)(ws + OFF_KEEP);

    (void)in_sizes; (void)n_in; (void)out_size; (void)ws_size; (void)WS_NEED;

    // zero hist + cnt + boxmax (ws is poisoned 0xAA before every call)
    hipMemsetAsync(d_ws, 0, ZERO_BYTES, stream);

    k_hist<<<B_IMGS * HBLK_PER_IMG, 512, 0, stream>>>(obj, hist);
    k_compact<<<B_IMGS * CBLK_PER_IMG, 256, 0, stream>>>(obj, hist, cnt, cand);
    k_sortlevel<<<NBL, 1024, 0, stream>>>(cand, cnt, sel);
    k_decode<<<dim3(5, B_IMGS), 1024, 0, stream>>>(
        deltas, anchors, sel, boxes_r, score_r, boxes_l, valid_l, rankmap, boxmax);
    k_nms<<<NBL, 1024, 0, stream>>>(boxes_l, valid_l, rankmap, boxmax, keep_r);
    k_output<<<B_IMGS, 256, 0, stream>>>(keep_r, boxes_r, score_r, out);
}

// Round 12
// 192.213 us; speedup vs baseline: 1.8273x; 1.8273x over previous
//
#include <hip/hip_runtime.h>
#include <stdint.h>

// Disable FMA contraction file-wide: we must replicate the reference's
// per-op f32 rounding (decode + IoU) to avoid NMS decision flips.
#pragma clang fp contract(off)

#define B_IMGS   4
#define NLVL     5
#define A_TOTAL  242991
#define NSEL     4741          // 1000*4 + 741
#define NBUCK    8192          // 13-bit buckets: sign+exp+4 mantissa (os>>19)
#define BSHIFT   19
#define CAND_CAP 2048
#define POST_NMS 1000
#define NBL      (B_IMGS * NLVL)
#define NMS_TH   0.7f
#define NEGV     (-1e10f)
#define W_IMGF   1216.0f
#define H_IMGF   800.0f
#define MIN_SZ   1e-3f
#define BBOX_CLIP 4.135166556742356f   // log(1000/16), rounded to f32 by compiler

// ---------- level helpers ----------
__device__ __forceinline__ int lvl_k(int l) { return (l == 4) ? 741 : 1000; }

// ---------- order-preserving float<->uint ----------
__device__ __forceinline__ unsigned flipf(float f) {
    unsigned u = __float_as_uint(f);
    return u ^ (unsigned)(((int)u >> 31) | 0x80000000);
}
__device__ __forceinline__ float unflipf(unsigned os) {
    unsigned u = (os & 0x80000000u) ? (os ^ 0x80000000u) : ~os;
    return __uint_as_float(u);
}

// ---------- async global->LDS DMA (16B per lane, wave-uniform LDS base) ----------
__device__ __forceinline__ void async_cp16(const void* g, void* l) {
    __builtin_amdgcn_global_load_lds(
        (const __attribute__((address_space(1))) unsigned*)g,
        (__attribute__((address_space(3))) unsigned*)l,
        16, 0, 0);
}

// ---------- workspace layout ----------
static constexpr size_t SZ_HIST    = (size_t)NBL * NBUCK * sizeof(unsigned);        // 655,360
static constexpr size_t OFF_CNT    = SZ_HIST;                                        // +80
static constexpr size_t OFF_BOXMAX = OFF_CNT + NBL * sizeof(unsigned);               // +16
static constexpr size_t ZERO_BYTES = OFF_BOXMAX + B_IMGS * sizeof(unsigned);
static constexpr size_t OFF_CAND   = (ZERO_BYTES + 15) & ~(size_t)15;
static constexpr size_t OFF_SEL    = OFF_CAND + (size_t)NBL * CAND_CAP * 8;
static constexpr size_t OFF_BOXR   = OFF_SEL + (size_t)B_IMGS * NSEL * 8;
static constexpr size_t OFF_SCR    = OFF_BOXR + (size_t)B_IMGS * NSEL * 16;
static constexpr size_t OFF_BOXL   = OFF_SCR + (size_t)B_IMGS * NSEL * 4;
static constexpr size_t OFF_VAL    = OFF_BOXL + (size_t)B_IMGS * NSEL * 16;
static constexpr size_t OFF_RMAP   = OFF_VAL + (size_t)B_IMGS * NSEL * 4;
static constexpr size_t OFF_KEEP   = OFF_RMAP + (size_t)B_IMGS * NSEL * 4;
static constexpr size_t OFF_MASK   = OFF_KEEP + (size_t)B_IMGS * NSEL * 4;           // 16-aligned
static constexpr size_t WS_NEED    = OFF_MASK + (size_t)NBL * 1024 * 16 * 8;         // ~4.7 MB

// ---------- K1: per-(b,level) LDS histogram, merged to global ----------
// 34 blocks per image, 512 threads, each covering one (level, sub-chunk) span.
#define HBLK_PER_IMG 34
__global__ void k_hist(const float* __restrict__ obj, unsigned* __restrict__ hist) {
    __shared__ unsigned lh[NBUCK];   // 32 KB
    const int tid = threadIdx.x;     // 512
    const int b = blockIdx.x / HBLK_PER_IMG;
    const int r = blockIdx.x - b * HBLK_PER_IMG;
    int l, sub, chunk, lstart, n;
    if (r < 24)      { l = 0; sub = r;      chunk = 7600; lstart = 0;      n = 182400; }
    else if (r < 30) { l = 1; sub = r - 24; chunk = 7600; lstart = 182400; n = 45600; }
    else if (r < 32) { l = 2; sub = r - 30; chunk = 5700; lstart = 228000; n = 11400; }
    else if (r == 32){ l = 3; sub = 0;      chunk = 2850; lstart = 239400; n = 2850; }
    else             { l = 4; sub = 0;      chunk = 741;  lstart = 242250; n = 741; }
    #pragma unroll
    for (int i = tid; i < NBUCK; i += 512) lh[i] = 0;
    __syncthreads();
    const int s0 = sub * chunk;
    const int cnt = min(chunk, n - s0);
    const float* src = obj + (size_t)b * A_TOTAL + lstart + s0;
    for (int i = tid; i < cnt; i += 512) {
        unsigned os = flipf(src[i]);
        atomicAdd(&lh[os >> BSHIFT], 1u);
    }
    __syncthreads();
    unsigned* gh = hist + (size_t)(b * NLVL + l) * NBUCK;
    for (int i = tid; i < NBUCK; i += 512) {
        unsigned v = lh[i];
        if (v) atomicAdd(&gh[i], v);
    }
}

// ---------- K2: compact candidates (threshold scan fused in-prologue) ----------
// One (b,level,sub-span) per block. Each block redundantly computes its bl's
// threshold from the global histogram (written by the PREVIOUS kernel ->
// kernel-boundary visibility). Passes staged in LDS, one global atomicAdd
// per block, coalesced copy-out. Order within cand[bl] is arbitrary.
#define CBLK_PER_IMG 65
__global__ void k_compact(const float* __restrict__ obj, const unsigned* __restrict__ hist,
                          unsigned* __restrict__ cnt, unsigned long long* __restrict__ cand) {
    __shared__ unsigned long long sbuf[CAND_CAP];   // 16 KB staging
    __shared__ unsigned part[256];
    __shared__ unsigned chunkbuf[32];
    __shared__ int s_chunk;
    __shared__ unsigned s_cum, s_thr, lcnt, gbase;
    const int tid = threadIdx.x;     // 256
    const int b = blockIdx.x / CBLK_PER_IMG;
    const int r = blockIdx.x - b * CBLK_PER_IMG;
    int l, sub, chunk, lstart, n;
    if (r < 48)      { l = 0; sub = r;      chunk = 3800; lstart = 0;      n = 182400; }
    else if (r < 60) { l = 1; sub = r - 48; chunk = 3800; lstart = 182400; n = 45600; }
    else if (r < 63) { l = 2; sub = r - 60; chunk = 3800; lstart = 228000; n = 11400; }
    else if (r == 63){ l = 3; sub = 0;      chunk = 2850; lstart = 239400; n = 2850; }
    else             { l = 4; sub = 0;      chunk = 741;  lstart = 242250; n = 741; }
    const int bl = b * NLVL + l;
    const int kl = lvl_k(l);
    // ---- fused threshold scan (identical in all blocks of this bl) ----
    const unsigned* h = hist + (size_t)bl * NBUCK;
    {
        unsigned s = 0;
        for (int i = 0; i < 32; ++i) s += h[tid * 32 + i];
        part[tid] = s;
    }
    if (tid == 0) lcnt = 0;
    __syncthreads();
    if (tid == 0) {
        unsigned cum = 0;
        int t = 255;
        for (; t > 0; --t) {
            if (cum + part[t] >= (unsigned)kl) break;
            cum += part[t];
        }
        s_chunk = t;
        s_cum = cum;
    }
    __syncthreads();
    if (tid < 32) chunkbuf[tid] = h[s_chunk * 32 + tid];
    __syncthreads();
    if (tid == 0) {
        unsigned c2 = s_cum;
        int T = s_chunk * 32;
        for (int i = 31; i >= 0; --i) {
            c2 += chunkbuf[i];
            if (c2 >= (unsigned)kl) { T = s_chunk * 32 + i; break; }
        }
        s_thr = (unsigned)T;
    }
    __syncthreads();
    const unsigned T = s_thr;
    // ---- pass filter into LDS staging ----
    const int s0 = sub * chunk;
    const int m = min(chunk, n - s0);
    const int abase = lstart + s0;
    const float* src = obj + (size_t)b * A_TOTAL + abase;
    for (int i = tid; i < m; i += 256) {
        unsigned os = flipf(src[i]);
        if ((os >> BSHIFT) >= T) {
            unsigned slot = atomicAdd(&lcnt, 1u);
            if (slot < CAND_CAP)
                sbuf[slot] = (((unsigned long long)(~os)) << 32) | (unsigned)(abase + i);
        }
    }
    __syncthreads();
    unsigned total = lcnt; if (total > CAND_CAP) total = CAND_CAP;
    if (tid == 0) gbase = atomicAdd(&cnt[bl], total);
    __syncthreads();
    const unsigned gb = gbase;
    for (unsigned i = tid; i < total; i += 256) {
        unsigned g = gb + i;
        if (g < CAND_CAP)
            cand[(size_t)bl * CAND_CAP + g] = sbuf[i];
    }
}

// ---------- K3: per-(b,level) bitonic sort of candidates; keep top-k ----------
// 512 threads (2 compare-swaps/thread/pass — latency-bound).
__global__ void k_sortlevel(const unsigned long long* __restrict__ cand,
                            const unsigned* __restrict__ cnt,
                            unsigned long long* __restrict__ sel) {
    __shared__ unsigned long long keys[CAND_CAP];
    const int bl = blockIdx.x;
    const int b = bl / NLVL, l = bl - (bl / NLVL) * NLVL;
    const int tid = threadIdx.x;
    int m = (int)cnt[bl];
    if (m > CAND_CAP) m = CAND_CAP;
    for (int i = tid; i < CAND_CAP; i += 512)
        keys[i] = (i < m) ? cand[(size_t)bl * CAND_CAP + i] : ~0ULL;
    __syncthreads();
    for (int k = 2; k <= CAND_CAP; k <<= 1) {
        for (int j = k >> 1; j > 0; j >>= 1) {
            for (int t = tid; t < CAND_CAP / 2; t += 512) {
                int i = ((t / j) * (j << 1)) + (t % j);
                int p = i + j;
                bool up = ((i & k) == 0);
                unsigned long long a = keys[i], c = keys[p];
                if ((a > c) == up) { keys[i] = c; keys[p] = a; }
            }
            __syncthreads();
        }
    }
    int kl = lvl_k(l);
    for (int q = tid; q < kl; q += 512)
        sel[(size_t)b * NSEL + l * 1000 + q] = keys[q];
}

// ---------- binary search in LDS: #elements < key ----------
__device__ __forceinline__ int lbound_lds(const unsigned long long* s, int len,
                                          unsigned long long key) {
    int lo = 0, hi = len;
    while (lo < hi) {
        int mid = (lo + hi) >> 1;
        if (s[mid] < key) lo = mid + 1; else hi = mid;
    }
    return lo;
}

// ---------- K4: decode+clip+valid; global rank via LDS 5-way merge-rank ----------
// grid (5, b) x 1024 threads — skey staged once per 1024 entries.
__global__ void k_decode(const float* __restrict__ deltas, const float* __restrict__ anchors,
                         const unsigned long long* __restrict__ sel,
                         float* __restrict__ boxes_r, float* __restrict__ score_r,
                         float* __restrict__ boxes_l, int* __restrict__ valid_l,
                         int* __restrict__ rankmap, unsigned* __restrict__ boxmax) {
    __shared__ unsigned long long skey[NSEL];     // 37,928 B
    __shared__ float wmax[16];
    const int b = blockIdx.y;
    const int tid = threadIdx.x;                  // 1024
    for (int i = tid; i < NSEL; i += 1024)
        skey[i] = sel[(size_t)b * NSEL + i];
    __syncthreads();

    int p = blockIdx.x * 1024 + tid;
    bool on = p < NSEL;
    float mx = 0.0f;
    if (on) {
        int l = p / 1000;           // p in [4000,4741) -> 4
        int q = p - l * 1000;
        unsigned long long key = skey[p];
        unsigned a = (unsigned)(key & 0xFFFFFFFFu);
        unsigned os = ~((unsigned)(key >> 32));
        if (a >= A_TOTAL) a = 0;    // impossible-path safety (MAX padding)
        float score = unflipf(os);
        // global rank = q + sum over other levels of (#keys < key)
        int r = q;
        for (int l2 = 0; l2 < NLVL; ++l2) {
            if (l2 == l) continue;
            r += lbound_lds(skey + l2 * 1000, lvl_k(l2), key);
        }
        // decode (replicates reference op order; contraction disabled)
        const float* dv = deltas + ((size_t)b * A_TOTAL + a) * 4;
        const float* av = anchors + (size_t)a * 4;
        float ax1 = av[0], ay1 = av[1], ax2 = av[2], ay2 = av[3];
        float wa = ax2 - ax1, ha = ay2 - ay1;
        float cxa = ax1 + 0.5f * wa, cya = ay1 + 0.5f * ha;
        float dx = dv[0], dy = dv[1];
        float dw = fminf(dv[2], BBOX_CLIP), dh = fminf(dv[3], BBOX_CLIP);
        float cx = dx * wa + cxa, cy = dy * ha + cya;
        float w = expf(dw) * wa, h = expf(dh) * ha;
        float x1 = cx - 0.5f * w, y1 = cy - 0.5f * h;
        float x2 = cx + 0.5f * w, y2 = cy + 0.5f * h;
        float x1c = fminf(fmaxf(x1, 0.0f), W_IMGF);
        float y1c = fminf(fmaxf(y1, 0.0f), H_IMGF);
        float x2c = fminf(fmaxf(x2, 0.0f), W_IMGF);
        float y2c = fminf(fmaxf(y2, 0.0f), H_IMGF);
        int valid = ((x2c - x1c) >= MIN_SZ) && ((y2c - y1c) >= MIN_SZ);
        mx = fmaxf(fmaxf(x1c, y1c), fmaxf(x2c, y2c));
        size_t rp = (size_t)b * NSEL + r;
        boxes_r[rp * 4 + 0] = x1c; boxes_r[rp * 4 + 1] = y1c;
        boxes_r[rp * 4 + 2] = x2c; boxes_r[rp * 4 + 3] = y2c;
        score_r[rp] = score;
        size_t pp = (size_t)b * NSEL + p;
        boxes_l[pp * 4 + 0] = x1c; boxes_l[pp * 4 + 1] = y1c;
        boxes_l[pp * 4 + 2] = x2c; boxes_l[pp * 4 + 3] = y2c;
        valid_l[pp] = valid;
        rankmap[pp] = r;
    }
    // block max reduction -> single device atomic (coords >= 0: bit order == value order)
    #pragma unroll
    for (int o = 32; o > 0; o >>= 1)
        mx = fmaxf(mx, __shfl_xor(mx, o));
    if ((tid & 63) == 0) wmax[tid >> 6] = mx;
    __syncthreads();
    if (tid == 0) {
        float m2 = wmax[0];
        #pragma unroll
        for (int i = 1; i < 16; ++i) m2 = fmaxf(m2, wmax[i]);
        atomicMax(boxmax + b, __float_as_uint(m2));
    }
}

// ---------- K5: suppression bitmask (per (b,level), offset-box IoU) ----------
// mask layout: [bl][row (1024 stride)][16 u64 words]
// 256 threads/block; one 64-box column tile shared by 4 row-tiles.
__global__ void k_mask(const float* __restrict__ boxes_l, const unsigned* __restrict__ boxmax,
                       unsigned long long* __restrict__ mask) {
    int bl = blockIdx.z;
    int b = bl / NLVL, l = bl - b * NLVL;
    int kl = lvl_k(l);
    int w = blockIdx.x, rg = blockIdx.y, tid = threadIdx.x;
    if (rg * 256 >= kl) return;              // whole block beyond level rows
    float M = __uint_as_float(boxmax[b]) + 1.0f;
    float off = (float)l * M;
    __shared__ float cb[64][5];
    int j0 = w * 64;
    if (tid < 64) {
        int j = j0 + tid;
        if (j < kl) {
            const float* bp = boxes_l + ((size_t)b * NSEL + l * 1000 + j) * 4;
            float x1 = bp[0] + off, y1 = bp[1] + off, x2 = bp[2] + off, y2 = bp[3] + off;
            cb[tid][0] = x1; cb[tid][1] = y1; cb[tid][2] = x2; cb[tid][3] = y2;
            cb[tid][4] = (x2 - x1) * (y2 - y1);
        }
    }
    __syncthreads();
    int i = rg * 256 + tid;
    if (i >= kl) return;
    unsigned long long word = 0;
    if (j0 + 63 > i) {
        const float* bp = boxes_l + ((size_t)b * NSEL + l * 1000 + i) * 4;
        float ix1 = bp[0] + off, iy1 = bp[1] + off, ix2 = bp[2] + off, iy2 = bp[3] + off;
        float ai = (ix2 - ix1) * (iy2 - iy1);
        int jmax = min(64, kl - j0);
        for (int bb = 0; bb < jmax; ++bb) {
            int jj = j0 + bb;
            if (jj <= i) continue;
            float ltx = fmaxf(ix1, cb[bb][0]), lty = fmaxf(iy1, cb[bb][1]);
            float rbx = fminf(ix2, cb[bb][2]), rby = fminf(iy2, cb[bb][3]);
            float ww = fmaxf(rbx - ltx, 0.0f), hh = fmaxf(rby - lty, 0.0f);
            float inter = ww * hh;
            float iou = inter / ((ai + cb[bb][4]) - inter);   // NaN>th == false, matches jnp
            if (iou > NMS_TH) word |= (1ULL << bb);
        }
    }
    mask[((size_t)bl * 1024 + i) * 16 + w] = word;
}

// ---------- K6: sequential greedy resolve (1 wave per (b,level)) ----------
// Serial loop visits ONLY rows with nonzero within-chunk diag word
// (rem &= ballot(diag != 0)) — zero-diag rows are greedy no-ops for kw.
// Mask chunks DMA'd to LDS via global_load_lds, double-buffered.
__global__ void k_resolve(const int* __restrict__ valid_l, const int* __restrict__ rankmap,
                          const unsigned long long* __restrict__ mask, int* __restrict__ keep_r) {
    const int bl = blockIdx.x;
    const int b = bl / NLVL, l = bl - b * NLVL;
    const int kl = lvl_k(l);
    const int lane = threadIdx.x;     // 64 threads = 1 wave
    __shared__ __align__(16) unsigned long long sbufA[64 * 16];  // 8 KB, mirror layout
    __shared__ __align__(16) unsigned long long sbufB[64 * 16];  // 8 KB
    const int base = b * NSEL + l * 1000;

    // keep word per chunk, distributed: lane w (w<16) holds chunk w's keep bits
    unsigned long long keep_w = 0;
    for (int c = 0; c < 16; ++c) {
        int q = c * 64 + lane;
        int vv = (q < kl) ? valid_l[base + q] : 0;
        unsigned long long bm = __ballot(vv);
        if (lane == c) keep_w = bm;
    }

    const int nch = (kl + 63) >> 6;   // 16 or 12
    const char* mbyte = (const char*)(mask + (size_t)bl * 1024 * 16);

    // DMA chunk 0 -> sbufA (8 x 1KB instructions; lane scatters 16B each)
    {
        const char* g0 = mbyte + (size_t)lane * 16;
        #pragma unroll
        for (int j = 0; j < 8; ++j)
            async_cp16(g0 + j * 1024, (char*)sbufA + j * 1024);
    }

    for (int c = 0; c < nch; ++c) {
        unsigned long long* cur = (c & 1) ? sbufB : sbufA;
        unsigned long long* nxt = (c & 1) ? sbufA : sbufB;
        __syncthreads();                       // drains vmcnt: chunk c staged
        if (c + 1 < nch) {
            const char* g1 = mbyte + (size_t)(c + 1) * 8192 + (size_t)lane * 16;
            #pragma unroll
            for (int j = 0; j < 8; ++j)
                async_cp16(g1 + j * 1024, (char*)nxt + j * 1024);
        }
        unsigned long long kw = __shfl(keep_w, c);   // uniform
        if (kw) {
            // diagonal word (word c of this lane's row): one conflicted read/chunk
            unsigned long long diag = cur[lane * 16 + c];
            unsigned dlo = (unsigned)diag, dhi = (unsigned)(diag >> 32);
            // rows with zero diag suppress nothing in-chunk: skip them wholesale
            unsigned long long nz = __ballot(diag != 0ULL);
            unsigned long long rem = kw & nz;
            while (rem) {
                int r = __ffsll((long long)rem) - 1;
                unsigned lo = __builtin_amdgcn_readlane(dlo, r);
                unsigned hi = __builtin_amdgcn_readlane(dhi, r);
                unsigned long long d = ((unsigned long long)hi << 32) | lo;
                kw &= ~d;
                rem &= ~(d | (1ULL << r));
            }
            // batched cross-chunk suppression: lane w<16 ORs word w of kept rows
            unsigned long long supp = 0;
            if (lane < 16) {
                #pragma unroll
                for (int r = 0; r < 64; ++r) {
                    unsigned long long m = cur[r * 16 + lane];
                    supp |= (((kw >> r) & 1ULL) ? m : 0ULL);
                }
            }
            if (lane == c) keep_w = kw;
            else if (lane < 16 && lane > c) keep_w &= ~supp;
        }
    }
    __syncthreads();
    // scatter keep bits to global-rank order
    for (int c = 0; c < 16; ++c) {
        unsigned long long kwc = __shfl(keep_w, c);
        int q = c * 64 + lane;
        if (q < kl)
            keep_r[b * NSEL + rankmap[base + q]] = (int)((kwc >> lane) & 1ULL);
    }
}

// ---------- K7: compact kept entries (score order) into output ----------
// v2: 1024 threads, CH=5 — shorter serial count/scatter tails per thread.
__global__ void k_output(const int* __restrict__ keep_r, const float* __restrict__ boxes_r,
                         const float* __restrict__ score_r, float* __restrict__ out) {
    int b = blockIdx.x, tid = threadIdx.x;    // 1024
    float* ob = out + (size_t)b * POST_NMS * 4;
    float* osc = out + (size_t)B_IMGS * POST_NMS * 4 + (size_t)b * POST_NMS;
    for (int p = tid; p < POST_NMS; p += 1024) {
        ob[p * 4 + 0] = 0.0f; ob[p * 4 + 1] = 0.0f;
        ob[p * 4 + 2] = 0.0f; ob[p * 4 + 3] = 0.0f;
        osc[p] = NEGV;
    }
    __syncthreads();   // global writes drained before barrier (vmcnt)
    const int CH = 5;  // 5*1024 = 5120 >= 4741
    int base = tid * CH;
    int cnt = 0;
    #pragma unroll
    for (int k = 0; k < CH; ++k) {
        int r = base + k;
        if (r < NSEL) cnt += keep_r[b * NSEL + r];
    }
    __shared__ int ps[1024];
    ps[tid] = cnt;
    __syncthreads();
    for (int ofs = 1; ofs < 1024; ofs <<= 1) {
        int v = (tid >= ofs) ? ps[tid - ofs] : 0;
        __syncthreads();
        ps[tid] += v;
        __syncthreads();
    }
    int p = ps[tid] - cnt;   // exclusive prefix
    #pragma unroll
    for (int k = 0; k < CH; ++k) {
        int r = base + k;
        if (r < NSEL && keep_r[b * NSEL + r]) {
            if (p < POST_NMS) {
                const float* bp = boxes_r + ((size_t)b * NSEL + r) * 4;
                ob[p * 4 + 0] = bp[0]; ob[p * 4 + 1] = bp[1];
                ob[p * 4 + 2] = bp[2]; ob[p * 4 + 3] = bp[3];
                osc[p] = score_r[(size_t)b * NSEL + r];
            }
            ++p;
        }
    }
}

extern "C" void kernel_launch(void* const* d_in, const int* in_sizes, int n_in,
                              void* d_out, int out_size, void* d_ws, size_t ws_size,
                              hipStream_t stream) {
    const float* obj     = (const float*)d_in[0];   // [4, 242991]
    const float* deltas  = (const float*)d_in[1];   // [4, 242991, 4]
    const float* anchors = (const float*)d_in[2];   // [242991, 4]
    float* out = (float*)d_out;                     // [4,1000,4] ++ [4,1000]

    char* ws = (char*)d_ws;
    unsigned*            hist    = (unsigned*)(ws);
    unsigned*            cnt     = (unsigned*)(ws + OFF_CNT);
    unsigned*            boxmax  = (unsigned*)(ws + OFF_BOXMAX);
    unsigned long long*  cand    = (unsigned long long*)(ws + OFF_CAND);
    unsigned long long*  sel     = (unsigned long long*)(ws + OFF_SEL);
    float*               boxes_r = (float*)(ws + OFF_BOXR);
    float*               score_r = (float*)(ws + OFF_SCR);
    float*               boxes_l = (float*)(ws + OFF_BOXL);
    int*                 valid_l = (int*)(ws + OFF_VAL);
    int*                 rankmap = (int*)(ws + OFF_RMAP);
    int*                 keep_r  = (int*)(ws + OFF_KEEP);
    unsigned long long*  maskp   = (unsigned long long*)(ws + OFF_MASK);

    (void)in_sizes; (void)n_in; (void)out_size; (void)ws_size; (void)WS_NEED;

    // zero hist + cnt + boxmax (ws is poisoned 0xAA before every call)
    hipMemsetAsync(d_ws, 0, ZERO_BYTES, stream);

    k_hist<<<B_IMGS * HBLK_PER_IMG, 512, 0, stream>>>(obj, hist);
    k_compact<<<B_IMGS * CBLK_PER_IMG, 256, 0, stream>>>(obj, hist, cnt, cand);
    k_sortlevel<<<NBL, 512, 0, stream>>>(cand, cnt, sel);
    k_decode<<<dim3(5, B_IMGS), 1024, 0, stream>>>(
        deltas, anchors, sel, boxes_r, score_r, boxes_l, valid_l, rankmap, boxmax);
    k_mask<<<dim3(16, 4, NBL), 256, 0, stream>>>(boxes_l, boxmax, maskp);
    k_resolve<<<NBL, 64, 0, stream>>>(valid_l, rankmap, maskp, keep_r);
    k_output<<<B_IMGS, 1024, 0, stream>>>(keep_r, boxes_r, score_r, out);
}